// Round 4
// baseline (369.093 us; speedup 1.0000x reference)
//
#include <hip/hip_runtime.h>
#include <hip/hip_bf16.h>

#define BATCH 4096
#define TSTEPS 256
#define NF 5
#define H 64
#define BT 16          // batch tile per block = 2 sub-tiles (P,Q) of 8
#define LDH 136        // hreg row stride in ushorts (272B)
#define NBLK (BATCH / BT)   // 256 blocks -> 1 block/CU

typedef __attribute__((ext_vector_type(8))) short bf16x8;
typedef __attribute__((ext_vector_type(4))) float f32x4;

#define LOG2E 1.4426950408889634f
#define TWOLOG2E 2.8853900817779268f

__device__ __forceinline__ ushort f2bf(float f) {
    union { float f; unsigned u; } v; v.f = f;
    unsigned u = v.u;
    unsigned r = (u + 0x7FFFu + ((u >> 16) & 1u)) >> 16;  // RNE
    return (ushort)r;
}
__device__ __forceinline__ float bf2f(ushort s) {
    union { unsigned u; float f; } v; v.u = ((unsigned)s) << 16;
    return v.f;
}
// preacts PRE-SCALED in weights: sigm rows by -log2e, tanh rows by +2log2e
__device__ __forceinline__ float sigm_s(float s) {           // s = -x*log2e
    return __builtin_amdgcn_rcpf(1.0f + __builtin_amdgcn_exp2f(s));
}
__device__ __forceinline__ float tanh_s(float s) {           // s = 2x*log2e
    return 1.0f - 2.0f * __builtin_amdgcn_rcpf(1.0f + __builtin_amdgcn_exp2f(s));
}

__global__ __launch_bounds__(256, 1)
void lstm2_kernel(const float* __restrict__ x,
                  const float* __restrict__ Wih0, const float* __restrict__ Whh0,
                  const float* __restrict__ bih0, const float* __restrict__ bhh0,
                  const float* __restrict__ Wih1, const float* __restrict__ Whh1,
                  const float* __restrict__ bih1, const float* __restrict__ bhh1,
                  const float* __restrict__ Wfc, const float* __restrict__ bfc,
                  float* __restrict__ out)
{
    __shared__ union {
        ushort xs[TSTEPS * BT * 8];   // bf16 x [t][tile][b8][8]; cols 5,6 = 1.0 (bias), 7 = 0
        float  hfin[BT * H];          // epilogue: fp32 final h1
    } uS;
    // per-tile bf16 state, single-buffered (reads/writes in different barrier phases)
    __shared__ ushort hreg[2][16 * LDH];  // [tile][row*LDH + col]; cols 0..63 h0, 64..127 h1

    const int tid = threadIdx.x;
    const int w   = tid >> 6;    // wave 0..3
    const int l   = tid & 63;
    const int g   = l >> 4;      // k-group / D-row group
    const int lr  = l & 15;      // A row / B,D col index
    const int bb  = blockIdx.x * BT;

    // ---- stage x for both tiles into LDS as bf16; pad cols 5,6 = 1.0 (bias) ----
    {
        const ushort one = f2bf(1.0f);
        for (int n = tid; n < TSTEPS * BT; n += 256) {
            const int tt = n >> 4, tb = n & 15;          // tb = tile*8 + b
            const float* xp = x + ((size_t)(bb + tb) * TSTEPS + tt) * NF;
            bf16x8 v;
            v[0] = (short)f2bf(xp[0]); v[1] = (short)f2bf(xp[1]);
            v[2] = (short)f2bf(xp[2]); v[3] = (short)f2bf(xp[3]);
            v[4] = (short)f2bf(xp[4]); v[5] = (short)one; v[6] = (short)one; v[7] = 0;
            *(bf16x8*)&uS.xs[n * 8] = v;
        }
    }
    for (int i = tid; i < 2 * 16 * LDH; i += 256) hreg[0][i] = 0;

    // ---- weight fragments resident in VGPRs, gate-scaled ----
    // wave w covers unit u = 16w+lr; gate gi at col n = 64*gi + u.
    // k-map (A and B): chunk c, group g, elem j -> k = 32c + 8g + j.
    const int u = 16 * w + lr;
    bf16x8 w0f[4][3], w1f[4][4];
    float b1v[4];
    #pragma unroll
    for (int gi = 0; gi < 4; ++gi) {
        const float sc = (gi == 2) ? TWOLOG2E : -LOG2E;
        const int n = 64 * gi + u;
        const float b0 = (bih0[n] + bhh0[n]) * sc;
        b1v[gi] = (bih1[n] + bhh1[n]) * sc;
        #pragma unroll
        for (int c = 0; c < 2; ++c) {                  // layer0 recurrent
            const float* p = Whh0 + n * H + 32 * c + 8 * g;
            bf16x8 v;
            #pragma unroll
            for (int j = 0; j < 8; ++j) v[j] = (short)f2bf(p[j] * sc);
            w0f[gi][c] = v;
        }
        {   // layer0 x-chunk: cols 0..4 Wih0 scaled; col5 bias_hi, col6 bias_lo
            const ushort bhi = f2bf(b0);
            const ushort blo = f2bf(b0 - bf2f(bhi));
            bf16x8 v;
            #pragma unroll
            for (int j = 0; j < 8; ++j) {
                int kk = 8 * g + j;
                ushort val = 0;
                if (kk < NF) val = f2bf(Wih0[n * NF + kk] * sc);
                else if (kk == 5) val = bhi;
                else if (kk == 6) val = blo;
                v[j] = (short)val;
            }
            w0f[gi][2] = v;
        }
        #pragma unroll
        for (int c = 0; c < 4; ++c) {                  // layer1: [Wih1 | Whh1]
            const float* p = (c < 2) ? (Wih1 + n * H + 32 * c + 8 * g)
                                     : (Whh1 + n * H + 32 * (c - 2) + 8 * g);
            bf16x8 v;
            #pragma unroll
            for (int j = 0; j < 8; ++j) v[j] = (short)f2bf(p[j] * sc);
            w1f[gi][c] = v;
        }
    }

    // lane group g owns sub-tile batches {2g, 2g+1} at sparse rows 4g+{0,1}
    const bool xlane = (g == 0) && ((lr & 2) == 0);
    const int  bx    = ((lr >> 2) << 1) | (lr & 1);    // batch-in-tile at row lr

    float c0P[2] = {0,0}, c1P[2] = {0,0}, c0Q[2] = {0,0}, c1Q[2] = {0,0};
    float h1fP[2] = {0,0}, h1fQ[2] = {0,0};
    f32x4 accP0[4], accP1[4], accQ0[4], accQ1[4];

    __syncthreads();

    const int arow = lr * LDH;

    auto mfma_phase = [&](int t, const ushort* __restrict__ hb, int tau,
                          f32x4* acc0, f32x4* acc1) {
        bf16x8 a00 = *(const bf16x8*)&hb[arow + 8 * g];        // h0 chunk 0
        bf16x8 a01 = *(const bf16x8*)&hb[arow + 32 + 8 * g];   // h0 chunk 1
        bf16x8 a12 = *(const bf16x8*)&hb[arow + 64 + 8 * g];   // h1 chunk 0
        bf16x8 a13 = *(const bf16x8*)&hb[arow + 96 + 8 * g];   // h1 chunk 1
        if (t < TSTEPS) {
            bf16x8 ax = {0, 0, 0, 0, 0, 0, 0, 0};
            if (xlane) ax = *(const bf16x8*)&uS.xs[((t * 2 + tau) * 8 + bx) * 8];
            #pragma unroll
            for (int gi = 0; gi < 4; ++gi) { f32x4 z = {0, 0, 0, 0}; acc0[gi] = z; }
            #pragma unroll
            for (int gi = 0; gi < 4; ++gi) acc0[gi] = __builtin_amdgcn_mfma_f32_16x16x32_bf16(a00, w0f[gi][0], acc0[gi], 0, 0, 0);
            #pragma unroll
            for (int gi = 0; gi < 4; ++gi) acc0[gi] = __builtin_amdgcn_mfma_f32_16x16x32_bf16(a01, w0f[gi][1], acc0[gi], 0, 0, 0);
            #pragma unroll
            for (int gi = 0; gi < 4; ++gi) acc0[gi] = __builtin_amdgcn_mfma_f32_16x16x32_bf16(ax,  w0f[gi][2], acc0[gi], 0, 0, 0);
        }
        if (t >= 1) {
            #pragma unroll
            for (int gi = 0; gi < 4; ++gi) { f32x4 a = {b1v[gi], b1v[gi], b1v[gi], b1v[gi]}; acc1[gi] = a; }
            #pragma unroll
            for (int gi = 0; gi < 4; ++gi) acc1[gi] = __builtin_amdgcn_mfma_f32_16x16x32_bf16(a00, w1f[gi][0], acc1[gi], 0, 0, 0);
            #pragma unroll
            for (int gi = 0; gi < 4; ++gi) acc1[gi] = __builtin_amdgcn_mfma_f32_16x16x32_bf16(a01, w1f[gi][1], acc1[gi], 0, 0, 0);
            #pragma unroll
            for (int gi = 0; gi < 4; ++gi) acc1[gi] = __builtin_amdgcn_mfma_f32_16x16x32_bf16(a12, w1f[gi][2], acc1[gi], 0, 0, 0);
            #pragma unroll
            for (int gi = 0; gi < 4; ++gi) acc1[gi] = __builtin_amdgcn_mfma_f32_16x16x32_bf16(a13, w1f[gi][3], acc1[gi], 0, 0, 0);
        }
    };

    auto ew_phase = [&](int t, ushort* __restrict__ hb,
                        const f32x4* acc0, const f32x4* acc1,
                        float* c0, float* c1, float* h1f) {
        if (t < TSTEPS) {
            #pragma unroll
            for (int r = 0; r < 2; ++r) {              // rows 4g+r, batches 2g+r
                float iv = sigm_s(acc0[0][r]);
                float fv = sigm_s(acc0[1][r]);
                float gv = tanh_s(acc0[2][r]);
                float ov = sigm_s(acc0[3][r]);
                float cc = fv * c0[r] + iv * gv;
                c0[r] = cc;
                float hh = ov * tanh_s(cc * TWOLOG2E);
                hb[(4 * g + r) * LDH + u] = f2bf(hh);
            }
        }
        if (t >= 1) {
            #pragma unroll
            for (int r = 0; r < 2; ++r) {
                float iv = sigm_s(acc1[0][r]);
                float fv = sigm_s(acc1[1][r]);
                float gv = tanh_s(acc1[2][r]);
                float ov = sigm_s(acc1[3][r]);
                float cc = fv * c1[r] + iv * gv;
                c1[r] = cc;
                float hh = ov * tanh_s(cc * TWOLOG2E);
                h1f[r] = hh;
                hb[(4 * g + r) * LDH + 64 + u] = f2bf(hh);
            }
        }
    };

    // Phase-interleaved two-tile pipeline, 2 barriers/step:
    //   A: MFMA_P(i)  ||  EW_Q(i-1)+write      (reads hreg[0]; writes hreg[1])
    //   B: MFMA_Q(i)  ||  EW_P(i)+write        (reads hreg[1]; writes hreg[0])
    #pragma unroll 1
    for (int i = 0; i <= TSTEPS; ++i) {
        mfma_phase(i, hreg[0], 0, accP0, accP1);
        if (i >= 1) ew_phase(i - 1, hreg[1], accQ0, accQ1, c0Q, c1Q, h1fQ);
        __syncthreads();
        mfma_phase(i, hreg[1], 1, accQ0, accQ1);
        ew_phase(i, hreg[0], accP0, accP1, c0P, c1P, h1fP);
        __syncthreads();
    }
    ew_phase(TSTEPS, hreg[1], accQ0, accQ1, c0Q, c1Q, h1fQ);   // drain Q's L1 final

    // epilogue: FC on fp32 final h1 (P = batches 0..7, Q = 8..15)
    #pragma unroll
    for (int r = 0; r < 2; ++r) {
        uS.hfin[(2 * g + r) * H + u]     = h1fP[r];
        uS.hfin[(8 + 2 * g + r) * H + u] = h1fQ[r];
    }
    __syncthreads();
    if (tid < BT * 2) {
        const int b = tid >> 1, cls = tid & 1;
        float s = bfc[cls];
        for (int k = 0; k < H; ++k) s += uS.hfin[b * H + k] * Wfc[cls * H + k];
        out[(size_t)(bb + b) * 2 + cls] = s;
    }
}

extern "C" void kernel_launch(void* const* d_in, const int* in_sizes, int n_in,
                              void* d_out, int out_size, void* d_ws, size_t ws_size,
                              hipStream_t stream) {
    const float* x    = (const float*)d_in[0];
    const float* Wih0 = (const float*)d_in[1];
    const float* Whh0 = (const float*)d_in[2];
    const float* bih0 = (const float*)d_in[3];
    const float* bhh0 = (const float*)d_in[4];
    const float* Wih1 = (const float*)d_in[5];
    const float* Whh1 = (const float*)d_in[6];
    const float* bih1 = (const float*)d_in[7];
    const float* bhh1 = (const float*)d_in[8];
    const float* Wfc  = (const float*)d_in[9];
    const float* bfc  = (const float*)d_in[10];
    float* out = (float*)d_out;

    lstm2_kernel<<<NBLK, 256, 0, stream>>>(x, Wih0, Whh0, bih0, bhh0,
                                           Wih1, Whh1, bih1, bhh1, Wfc, bfc, out);
}

// Round 5
// 300.985 us; speedup vs baseline: 1.2263x; 1.2263x over previous
//
#include <hip/hip_runtime.h>
#include <hip/hip_bf16.h>
#include <math.h>

#define BATCH 4096
#define TSTEPS 256
#define NF 5
#define H 64
#define BT 8           // batch tile per block (sparse rows 0,1,4,5,8,9,12,13)
#define LDH 136        // hreg row stride in ushorts
#define NBLK (BATCH / BT)   // 512 blocks -> 2 blocks/CU -> 2 waves/SIMD

typedef __attribute__((ext_vector_type(8))) short bf16x8;
typedef __attribute__((ext_vector_type(4))) float f32x4;

__device__ __forceinline__ ushort f2bf(float f) {
    union { float f; unsigned u; } v; v.f = f;
    unsigned u = v.u;
    unsigned r = (u + 0x7FFFu + ((u >> 16) & 1u)) >> 16;  // RNE
    return (ushort)r;
}
__device__ __forceinline__ float bf2f(ushort s) {
    union { unsigned u; float f; } v; v.u = ((unsigned)s) << 16;
    return v.f;
}

__global__ __launch_bounds__(256, 2)
void lstm2_kernel(const float* __restrict__ x,
                  const float* __restrict__ Wih0, const float* __restrict__ Whh0,
                  const float* __restrict__ bih0, const float* __restrict__ bhh0,
                  const float* __restrict__ Wih1, const float* __restrict__ Whh1,
                  const float* __restrict__ bih1, const float* __restrict__ bhh1,
                  const float* __restrict__ Wfc, const float* __restrict__ bfc,
                  float* __restrict__ out)
{
    __shared__ union {
        ushort xs[TSTEPS * BT * 8];   // bf16 x [t][b][8]; cols 5,6 = 1.0 (bias), 7 = 0
        float  hfin[BT * H];          // epilogue: fp32 final h1
    } uS;
    __shared__ ushort hreg[2][16 * LDH];  // dbuf state; cols 0..63 h0, 64..127 h1
    // activation tables: (value, slope) f32 pairs.
    //   sig : [0..1023]  x in [-16,16], idx = 32x+512
    //   tanh: [1024..1535] offset 2048 floats, x in [-8,8], idx = 32x+256
    __shared__ float tabs[3072];

    const int tid = threadIdx.x;
    const int w   = tid >> 6;    // wave 0..3
    const int l   = tid & 63;
    const int g   = l >> 4;      // k-group / D-row group
    const int lr  = l & 15;      // A row / B,D col index
    const int bb  = blockIdx.x * BT;

    // ---- build activation tables ----
    for (int i = tid; i < 1536; i += 256) {
        float x0, v0, v1; float* dst;
        if (i < 1024) {
            x0 = (float)(i - 512) * 0.03125f;
            v0 = 1.0f / (1.0f + __expf(-x0));
            v1 = 1.0f / (1.0f + __expf(-(x0 + 0.03125f)));
            dst = &tabs[2 * i];
        } else {
            int j = i - 1024;
            x0 = (float)(j - 256) * 0.03125f;
            v0 = tanhf(x0);
            v1 = tanhf(x0 + 0.03125f);
            dst = &tabs[2048 + 2 * j];
        }
        dst[0] = v0; dst[1] = v1 - v0;
    }

    // ---- stage x tile into LDS as bf16; pad cols 5,6 = 1.0 (bias cols) ----
    {
        const int b  = tid & 7;
        const int t0 = tid >> 3;
        const ushort one = f2bf(1.0f);
        for (int tt = t0; tt < TSTEPS; tt += 32) {
            const float* xp = x + ((size_t)(bb + b) * TSTEPS + tt) * NF;
            bf16x8 v;
            v[0] = (short)f2bf(xp[0]); v[1] = (short)f2bf(xp[1]);
            v[2] = (short)f2bf(xp[2]); v[3] = (short)f2bf(xp[3]);
            v[4] = (short)f2bf(xp[4]); v[5] = (short)one; v[6] = (short)one; v[7] = 0;
            *(bf16x8*)&uS.xs[(tt * BT + b) * 8] = v;
        }
    }
    for (int i = tid; i < 2 * 16 * LDH; i += 256) hreg[0][i] = 0;

    // ---- weight fragments resident in VGPRs (unscaled) ----
    // wave w covers unit u = 16w+lr; gate gi at col n = 64*gi + u.
    // k-map (A and B): chunk c, group g, elem j -> k = 32c + 8g + j.
    const int u = 16 * w + lr;
    bf16x8 w0f[4][3], w1f[4][4];
    float b1v[4];
    #pragma unroll
    for (int gi = 0; gi < 4; ++gi) {
        const int n = 64 * gi + u;
        const float b0 = bih0[n] + bhh0[n];
        b1v[gi] = bih1[n] + bhh1[n];
        #pragma unroll
        for (int c = 0; c < 2; ++c) {                  // layer0 recurrent
            const float* p = Whh0 + n * H + 32 * c + 8 * g;
            bf16x8 v;
            #pragma unroll
            for (int j = 0; j < 8; ++j) v[j] = (short)f2bf(p[j]);
            w0f[gi][c] = v;
        }
        {   // layer0 x-chunk: cols 0..4 Wih0; col5 bias_hi, col6 bias_lo
            const ushort bhi = f2bf(b0);
            const ushort blo = f2bf(b0 - bf2f(bhi));
            bf16x8 v;
            #pragma unroll
            for (int j = 0; j < 8; ++j) {
                int kk = 8 * g + j;
                ushort val = 0;
                if (kk < NF) val = f2bf(Wih0[n * NF + kk]);
                else if (kk == 5) val = bhi;
                else if (kk == 6) val = blo;
                v[j] = (short)val;
            }
            w0f[gi][2] = v;
        }
        #pragma unroll
        for (int c = 0; c < 4; ++c) {                  // layer1: [Wih1 | Whh1]
            const float* p = (c < 2) ? (Wih1 + n * H + 32 * c + 8 * g)
                                     : (Whh1 + n * H + 32 * (c - 2) + 8 * g);
            bf16x8 v;
            #pragma unroll
            for (int j = 0; j < 8; ++j) v[j] = (short)f2bf(p[j]);
            w1f[gi][c] = v;
        }
    }

    // LUT lookups (LDS, value+slope linear interp)
    auto SIG = [&](float xx) -> float {
        float uu = fmaf(xx, 32.0f, 512.0f);
        uu = fminf(fmaxf(uu, 0.0f), 1023.0f);
        float uf = truncf(uu);
        int i = (int)uf;
        float fr = uu - uf;
        return fmaf(tabs[2 * i + 1], fr, tabs[2 * i]);
    };
    auto TANH = [&](float xx) -> float {
        float uu = fmaf(xx, 32.0f, 256.0f);
        uu = fminf(fmaxf(uu, 0.0f), 511.0f);
        float uf = truncf(uu);
        int i = (int)uf;
        float fr = uu - uf;
        return fmaf(tabs[2048 + 2 * i + 1], fr, tabs[2048 + 2 * i]);
    };

    // lane group g owns batches {2g, 2g+1} at sparse rows 4g+{0,1}
    float c0[2] = {0, 0}, c1[2] = {0, 0};
    float h1fin[2] = {0, 0};
    const bool xlane = (g == 0) && ((lr & 2) == 0);
    const int  bx    = ((lr >> 2) << 1) | (lr & 1);    // batch at row lr

    __syncthreads();

    const int arow = lr * LDH;
    const f32x4 kZ = {0, 0, 0, 0};

    // Pipelined: iteration t = layer0 step t (h0[t-1], x[t]) + layer1 step t-1.
    // Double-buffered hreg -> ONE barrier per iteration.
    auto body = [&](int t, const ushort* __restrict__ rb, ushort* __restrict__ wb) {
        const bool do0 = (t < TSTEPS);
        const bool do1 = (t >= 1);

        bf16x8 a00 = *(const bf16x8*)&rb[arow + 8 * g];        // h0 chunk 0
        bf16x8 a01 = *(const bf16x8*)&rb[arow + 32 + 8 * g];   // h0 chunk 1
        bf16x8 a12, a13;
        if (do1) {
            a12 = *(const bf16x8*)&rb[arow + 64 + 8 * g];      // h1 chunk 0
            a13 = *(const bf16x8*)&rb[arow + 96 + 8 * g];      // h1 chunk 1
        }
        bf16x8 ax = {0, 0, 0, 0, 0, 0, 0, 0};
        if (do0 && xlane) ax = *(const bf16x8*)&uS.xs[(t * BT + bx) * 8];

        f32x4 acc0[4], acc1[4];
        if (do0) {
            #pragma unroll
            for (int gi = 0; gi < 4; ++gi) acc0[gi] = __builtin_amdgcn_mfma_f32_16x16x32_bf16(a00, w0f[gi][0], kZ, 0, 0, 0);
            #pragma unroll
            for (int gi = 0; gi < 4; ++gi) acc0[gi] = __builtin_amdgcn_mfma_f32_16x16x32_bf16(a01, w0f[gi][1], acc0[gi], 0, 0, 0);
            #pragma unroll
            for (int gi = 0; gi < 4; ++gi) acc0[gi] = __builtin_amdgcn_mfma_f32_16x16x32_bf16(ax,  w0f[gi][2], acc0[gi], 0, 0, 0);
        }
        if (do1) {
            #pragma unroll
            for (int gi = 0; gi < 4; ++gi) acc1[gi] = __builtin_amdgcn_mfma_f32_16x16x32_bf16(a00, w1f[gi][0], kZ, 0, 0, 0);
            #pragma unroll
            for (int gi = 0; gi < 4; ++gi) acc1[gi] = __builtin_amdgcn_mfma_f32_16x16x32_bf16(a01, w1f[gi][1], acc1[gi], 0, 0, 0);
            #pragma unroll
            for (int gi = 0; gi < 4; ++gi) acc1[gi] = __builtin_amdgcn_mfma_f32_16x16x32_bf16(a12, w1f[gi][2], acc1[gi], 0, 0, 0);
            #pragma unroll
            for (int gi = 0; gi < 4; ++gi) acc1[gi] = __builtin_amdgcn_mfma_f32_16x16x32_bf16(a13, w1f[gi][3], acc1[gi], 0, 0, 0);
        }

        if (do0) {
            #pragma unroll
            for (int r = 0; r < 2; ++r) {              // rows 4g+r, batches 2g+r
                float iv = SIG(acc0[0][r]);
                float fv = SIG(acc0[1][r]);
                float gv = TANH(acc0[2][r]);
                float ov = SIG(acc0[3][r]);
                float cc = fmaf(fv, c0[r], iv * gv);
                c0[r] = cc;
                float hh = ov * TANH(cc);
                wb[(4 * g + r) * LDH + u] = f2bf(hh);
            }
        }
        if (do1) {
            #pragma unroll
            for (int r = 0; r < 2; ++r) {
                float iv = SIG(acc1[0][r] + b1v[0]);
                float fv = SIG(acc1[1][r] + b1v[1]);
                float gv = TANH(acc1[2][r] + b1v[2]);
                float ov = SIG(acc1[3][r] + b1v[3]);
                float cc = fmaf(fv, c1[r], iv * gv);
                c1[r] = cc;
                float hh = ov * TANH(cc);
                h1fin[r] = hh;
                wb[(4 * g + r) * LDH + 64 + u] = f2bf(hh);
            }
        }
        __syncthreads();
    };

    #pragma unroll 1
    for (int t = 0; t < TSTEPS; t += 2) {
        body(t,     hreg[0], hreg[1]);
        body(t + 1, hreg[1], hreg[0]);
    }
    body(TSTEPS, hreg[0], hreg[1]);   // drain: layer1 step T-1

    // epilogue: FC on fp32 final h1
    #pragma unroll
    for (int r = 0; r < 2; ++r) uS.hfin[(2 * g + r) * H + u] = h1fin[r];
    __syncthreads();
    if (tid < BT * 2) {
        const int b = tid >> 1, cls = tid & 1;
        float s = bfc[cls];
        for (int k = 0; k < H; ++k) s += uS.hfin[b * H + k] * Wfc[cls * H + k];
        out[(size_t)(bb + b) * 2 + cls] = s;
    }
}

extern "C" void kernel_launch(void* const* d_in, const int* in_sizes, int n_in,
                              void* d_out, int out_size, void* d_ws, size_t ws_size,
                              hipStream_t stream) {
    const float* x    = (const float*)d_in[0];
    const float* Wih0 = (const float*)d_in[1];
    const float* Whh0 = (const float*)d_in[2];
    const float* bih0 = (const float*)d_in[3];
    const float* bhh0 = (const float*)d_in[4];
    const float* Wih1 = (const float*)d_in[5];
    const float* Whh1 = (const float*)d_in[6];
    const float* bih1 = (const float*)d_in[7];
    const float* bhh1 = (const float*)d_in[8];
    const float* Wfc  = (const float*)d_in[9];
    const float* bfc  = (const float*)d_in[10];
    float* out = (float*)d_out;

    lstm2_kernel<<<NBLK, 256, 0, stream>>>(x, Wih0, Whh0, bih0, bhh0,
                                           Wih1, Whh1, bih1, bhh1, Wfc, bfc, out);
}

// Round 6
// 247.736 us; speedup vs baseline: 1.4899x; 1.2149x over previous
//
#include <hip/hip_runtime.h>
#include <hip/hip_bf16.h>

#define BATCH 4096
#define TSTEPS 256
#define NF 5
#define H 64
#define BT 8           // batch tile per block (sparse rows 0,1,4,5,8,9,12,13)
#define LDH 136        // hreg row stride in ushorts
#define NBLK (BATCH / BT)   // 512 blocks -> 2 blocks/CU -> 2 waves/SIMD

typedef __attribute__((ext_vector_type(8))) short bf16x8;
typedef __attribute__((ext_vector_type(4))) float f32x4;

#define LOG2E 1.4426950408889634f
#define TWOLOG2E 2.8853900817779268f

__device__ __forceinline__ ushort f2bf(float f) {
    union { float f; unsigned u; } v; v.f = f;
    unsigned u = v.u;
    unsigned r = (u + 0x7FFFu + ((u >> 16) & 1u)) >> 16;  // RNE
    return (ushort)r;
}
__device__ __forceinline__ float bf2f(ushort s) {
    union { unsigned u; float f; } v; v.u = ((unsigned)s) << 16;
    return v.f;
}
// preacts PRE-SCALED in weights: sigm rows by -log2e, tanh rows by +2log2e
__device__ __forceinline__ float sigm_s(float s) {           // s = -x*log2e
    return __builtin_amdgcn_rcpf(1.0f + __builtin_amdgcn_exp2f(s));
}
__device__ __forceinline__ float tanh_s(float s) {           // s = 2x*log2e
    return 1.0f - 2.0f * __builtin_amdgcn_rcpf(1.0f + __builtin_amdgcn_exp2f(s));
}
// pack two fp32 -> two bf16 (RNE) in one instruction
__device__ __forceinline__ unsigned pk_bf16(float lo, float hi) {
    unsigned pk;
    asm("v_cvt_pk_bf16_f32 %0, %1, %2" : "=v"(pk) : "v"(lo), "v"(hi));
    return pk;
}

__global__ __launch_bounds__(256, 2)
void lstm2_kernel(const float* __restrict__ x,
                  const float* __restrict__ Wih0, const float* __restrict__ Whh0,
                  const float* __restrict__ bih0, const float* __restrict__ bhh0,
                  const float* __restrict__ Wih1, const float* __restrict__ Whh1,
                  const float* __restrict__ bih1, const float* __restrict__ bhh1,
                  const float* __restrict__ Wfc, const float* __restrict__ bfc,
                  float* __restrict__ out)
{
    __shared__ union {
        ushort xs[TSTEPS * BT * 8];   // bf16 x [t][b][8]; cols 5,6 = 1.0 (bias), 7 = 0
        float  hfin[BT * H];          // epilogue: fp32 final h1
    } uS;
    __shared__ ushort hreg[2][16 * LDH];  // dbuf state; cols 0..63 h0, 64..127 h1

    const int tid = threadIdx.x;
    const int w   = tid >> 6;    // wave 0..3
    const int l   = tid & 63;
    const int g   = l >> 4;      // k-group / D-row group
    const int lr  = l & 15;      // A row / B,D col index
    const int bb  = blockIdx.x * BT;

    // ---- stage x tile into LDS as bf16; pad cols 5,6 = 1.0 (bias cols) ----
    {
        const int b  = tid & 7;
        const int t0 = tid >> 3;
        const ushort one = f2bf(1.0f);
        for (int tt = t0; tt < TSTEPS; tt += 32) {
            const float* xp = x + ((size_t)(bb + b) * TSTEPS + tt) * NF;
            bf16x8 v;
            v[0] = (short)f2bf(xp[0]); v[1] = (short)f2bf(xp[1]);
            v[2] = (short)f2bf(xp[2]); v[3] = (short)f2bf(xp[3]);
            v[4] = (short)f2bf(xp[4]); v[5] = (short)one; v[6] = (short)one; v[7] = 0;
            *(bf16x8*)&uS.xs[(tt * BT + b) * 8] = v;
        }
    }
    for (int i = tid; i < 2 * 16 * LDH; i += 256) hreg[0][i] = 0;

    // ---- weight fragments resident in VGPRs, gate-scaled ----
    // wave w covers unit u = 16w+lr; gate gi at col n = 64*gi + u.
    // k-map (A and B): chunk c, group g, elem j -> k = 32c + 8g + j.
    const int u = 16 * w + lr;
    bf16x8 w0f[4][3], w1f[4][4];
    f32x4 b1acc[4];                     // persistent L1-bias accumulator C-operands
    #pragma unroll
    for (int gi = 0; gi < 4; ++gi) {
        const float sc = (gi == 2) ? TWOLOG2E : -LOG2E;
        const int n = 64 * gi + u;
        const float b0 = (bih0[n] + bhh0[n]) * sc;
        const float b1 = (bih1[n] + bhh1[n]) * sc;
        { f32x4 a = {b1, b1, b1, b1}; b1acc[gi] = a; }
        #pragma unroll
        for (int c = 0; c < 2; ++c) {                  // layer0 recurrent
            const float* p = Whh0 + n * H + 32 * c + 8 * g;
            bf16x8 v;
            #pragma unroll
            for (int j = 0; j < 8; ++j) v[j] = (short)f2bf(p[j] * sc);
            w0f[gi][c] = v;
        }
        {   // layer0 x-chunk: cols 0..4 Wih0 scaled; col5 bias_hi, col6 bias_lo
            const ushort bhi = f2bf(b0);
            const ushort blo = f2bf(b0 - bf2f(bhi));
            bf16x8 v;
            #pragma unroll
            for (int j = 0; j < 8; ++j) {
                int kk = 8 * g + j;
                ushort val = 0;
                if (kk < NF) val = f2bf(Wih0[n * NF + kk] * sc);
                else if (kk == 5) val = bhi;
                else if (kk == 6) val = blo;
                v[j] = (short)val;
            }
            w0f[gi][2] = v;
        }
        #pragma unroll
        for (int c = 0; c < 4; ++c) {                  // layer1: [Wih1 | Whh1]
            const float* p = (c < 2) ? (Wih1 + n * H + 32 * c + 8 * g)
                                     : (Whh1 + n * H + 32 * (c - 2) + 8 * g);
            bf16x8 v;
            #pragma unroll
            for (int j = 0; j < 8; ++j) v[j] = (short)f2bf(p[j] * sc);
            w1f[gi][c] = v;
        }
    }

    // lane group g owns batches {2g, 2g+1} at sparse rows 4g+{0,1}
    float c0[2] = {0, 0}, c1[2] = {0, 0};
    float h1fin[2] = {0, 0};
    const bool xlane = (g == 0) && ((lr & 2) == 0);
    const int  bx    = ((lr >> 2) << 1) | (lr & 1);    // batch at row lr

    __syncthreads();

    // anti-phase stagger: offset odd blocks ~half a step so the two co-resident
    // blocks' EW (trans-heavy) and MFMA/stall phases interleave instead of colliding
    if (blockIdx.x & 1) __builtin_amdgcn_s_sleep(16);

    const int arow = lr * LDH;
    const f32x4 kZ = {0, 0, 0, 0};

    // Pipelined: iteration t = layer0 step t (h0[t-1], x[t]) + layer1 step t-1.
    // Double-buffered hreg -> ONE barrier per iteration.
    auto body = [&](int t, const ushort* __restrict__ rb, ushort* __restrict__ wb) {
        const bool do0 = (t < TSTEPS);
        const bool do1 = (t >= 1);

        bf16x8 a00 = *(const bf16x8*)&rb[arow + 8 * g];        // h0 chunk 0
        bf16x8 a01 = *(const bf16x8*)&rb[arow + 32 + 8 * g];   // h0 chunk 1
        bf16x8 a12, a13;
        if (do1) {
            a12 = *(const bf16x8*)&rb[arow + 64 + 8 * g];      // h1 chunk 0
            a13 = *(const bf16x8*)&rb[arow + 96 + 8 * g];      // h1 chunk 1
        }
        bf16x8 ax = {0, 0, 0, 0, 0, 0, 0, 0};
        if (do0 && xlane) ax = *(const bf16x8*)&uS.xs[(t * BT + bx) * 8];

        f32x4 acc0[4], acc1[4];
        if (do0) {
            #pragma unroll
            for (int gi = 0; gi < 4; ++gi) acc0[gi] = __builtin_amdgcn_mfma_f32_16x16x32_bf16(a00, w0f[gi][0], kZ, 0, 0, 0);
            #pragma unroll
            for (int gi = 0; gi < 4; ++gi) acc0[gi] = __builtin_amdgcn_mfma_f32_16x16x32_bf16(a01, w0f[gi][1], acc0[gi], 0, 0, 0);
            #pragma unroll
            for (int gi = 0; gi < 4; ++gi) acc0[gi] = __builtin_amdgcn_mfma_f32_16x16x32_bf16(ax,  w0f[gi][2], acc0[gi], 0, 0, 0);
        }
        if (do1) {
            #pragma unroll
            for (int gi = 0; gi < 4; ++gi) acc1[gi] = __builtin_amdgcn_mfma_f32_16x16x32_bf16(a00, w1f[gi][0], b1acc[gi], 0, 0, 0);
            #pragma unroll
            for (int gi = 0; gi < 4; ++gi) acc1[gi] = __builtin_amdgcn_mfma_f32_16x16x32_bf16(a01, w1f[gi][1], acc1[gi], 0, 0, 0);
            #pragma unroll
            for (int gi = 0; gi < 4; ++gi) acc1[gi] = __builtin_amdgcn_mfma_f32_16x16x32_bf16(a12, w1f[gi][2], acc1[gi], 0, 0, 0);
            #pragma unroll
            for (int gi = 0; gi < 4; ++gi) acc1[gi] = __builtin_amdgcn_mfma_f32_16x16x32_bf16(a13, w1f[gi][3], acc1[gi], 0, 0, 0);
        }

        if (do0) {
            float hh[2];
            #pragma unroll
            for (int r = 0; r < 2; ++r) {              // rows 4g+r, batches 2g+r
                float iv = sigm_s(acc0[0][r]);
                float fv = sigm_s(acc0[1][r]);
                float gv = tanh_s(acc0[2][r]);
                float ov = sigm_s(acc0[3][r]);
                float cc = fmaf(fv, c0[r], iv * gv);
                c0[r] = cc;
                hh[r] = ov * tanh_s(cc * TWOLOG2E);
            }
            unsigned pk = pk_bf16(hh[0], hh[1]);
            wb[(4 * g + 0) * LDH + u] = (ushort)pk;
            wb[(4 * g + 1) * LDH + u] = (ushort)(pk >> 16);
        }
        if (do1) {
            float hh[2];
            #pragma unroll
            for (int r = 0; r < 2; ++r) {
                float iv = sigm_s(acc1[0][r]);
                float fv = sigm_s(acc1[1][r]);
                float gv = tanh_s(acc1[2][r]);
                float ov = sigm_s(acc1[3][r]);
                float cc = fmaf(fv, c1[r], iv * gv);
                c1[r] = cc;
                hh[r] = ov * tanh_s(cc * TWOLOG2E);
                h1fin[r] = hh[r];
            }
            unsigned pk = pk_bf16(hh[0], hh[1]);
            wb[(4 * g + 0) * LDH + 64 + u] = (ushort)pk;
            wb[(4 * g + 1) * LDH + 64 + u] = (ushort)(pk >> 16);
        }
        __syncthreads();
    };

    #pragma unroll 1
    for (int t = 0; t < TSTEPS; t += 2) {
        body(t,     hreg[0], hreg[1]);
        body(t + 1, hreg[1], hreg[0]);
    }
    body(TSTEPS, hreg[0], hreg[1]);   // drain: layer1 step T-1

    // epilogue: FC on fp32 final h1
    #pragma unroll
    for (int r = 0; r < 2; ++r) uS.hfin[(2 * g + r) * H + u] = h1fin[r];
    __syncthreads();
    if (tid < BT * 2) {
        const int b = tid >> 1, cls = tid & 1;
        float s = bfc[cls];
        for (int k = 0; k < H; ++k) s += uS.hfin[b * H + k] * Wfc[cls * H + k];
        out[(size_t)(bb + b) * 2 + cls] = s;
    }
}

extern "C" void kernel_launch(void* const* d_in, const int* in_sizes, int n_in,
                              void* d_out, int out_size, void* d_ws, size_t ws_size,
                              hipStream_t stream) {
    const float* x    = (const float*)d_in[0];
    const float* Wih0 = (const float*)d_in[1];
    const float* Whh0 = (const float*)d_in[2];
    const float* bih0 = (const float*)d_in[3];
    const float* bhh0 = (const float*)d_in[4];
    const float* Wih1 = (const float*)d_in[5];
    const float* Whh1 = (const float*)d_in[6];
    const float* bih1 = (const float*)d_in[7];
    const float* bhh1 = (const float*)d_in[8];
    const float* Wfc  = (const float*)d_in[9];
    const float* bfc  = (const float*)d_in[10];
    float* out = (float*)d_out;

    lstm2_kernel<<<NBLK, 256, 0, stream>>>(x, Wih0, Whh0, bih0, bhh0,
                                           Wih1, Whh1, bih1, bhh1, Wfc, bfc, out);
}